// Round 3
// baseline (370.570 us; speedup 1.0000x reference)
//
#include <hip/hip_runtime.h>

// SGConv: K=3 hops of \hat{A} x (symmetric gcn_norm w/ self-loops), then Linear.
// N=100000, E=1600000, F_in=32, F_out=64.
// Round 3: (a) drop per-edge weight array via g = dinv .* h re-association
//   (hop: g' = dinv^2 * (sum g[src] + g[self]); last hop scales by dinv once)
//   -> k_fill scatters only `col` (halves write-allocate traffic);
// (b) hop gather: 32 lanes/row (4 edge stripes x 8 f4 lanes) + shfl reduce
//   -> less degree-divergence waste, pure-add inner loop.

#define F_IN 32
#define F_OUT 64
#define SCAN_B 256

typedef float f4 __attribute__((ext_vector_type(4)));

__global__ void k_count_deg(const int* __restrict__ dst, int* deg, int E) {
    int e = blockIdx.x * blockDim.x + threadIdx.x;
    if (e < E) atomicAdd(&deg[dst[e]], 1);
}

__global__ void k_dinv(const int* __restrict__ deg, float* __restrict__ dinv, int N) {
    int i = blockIdx.x * blockDim.x + threadIdx.x;
    if (i < N) dinv[i] = rsqrtf(1.0f + (float)deg[i]);  // +1 self-loop
}

// Per-block inclusive scan of deg -> rp[i+1]; block totals -> bsum.
__global__ __launch_bounds__(SCAN_B) void k_scan_block(const int* __restrict__ deg,
                                                       int* __restrict__ rp,
                                                       int* __restrict__ bsum, int N) {
    __shared__ int s[SCAN_B];
    int tid = threadIdx.x;
    int i = blockIdx.x * SCAN_B + tid;
    int v = (i < N) ? deg[i] : 0;
    s[tid] = v;
    __syncthreads();
    for (int off = 1; off < SCAN_B; off <<= 1) {
        int t = (tid >= off) ? s[tid - off] : 0;
        __syncthreads();
        s[tid] += t;
        __syncthreads();
    }
    if (i < N) rp[i + 1] = s[tid];
    if (tid == SCAN_B - 1) bsum[blockIdx.x] = s[tid];
}

__global__ __launch_bounds__(512) void k_scan_bsums(int* __restrict__ bsum, int nb) {
    __shared__ int s[512];
    int tid = threadIdx.x;
    int v = (tid < nb) ? bsum[tid] : 0;
    s[tid] = v;
    __syncthreads();
    for (int off = 1; off < 512; off <<= 1) {
        int t = (tid >= off) ? s[tid - off] : 0;
        __syncthreads();
        s[tid] += t;
        __syncthreads();
    }
    if (tid < nb) bsum[tid] = s[tid] - v;  // exclusive
}

__global__ void k_scan_final(int* __restrict__ rp, const int* __restrict__ bsum, int N) {
    int i = blockIdx.x * blockDim.x + threadIdx.x;
    if (i == 0) rp[0] = 0;
    if (i < N) rp[i + 1] += bsum[i >> 8];  // SCAN_B == 256
}

// Scatter edge sources into CSR slots (col only — no weight array).
__global__ void k_fill(const int* __restrict__ ei, const int* __restrict__ rp,
                       int* tmp, int* __restrict__ col, int E) {
    int e = blockIdx.x * blockDim.x + threadIdx.x;
    if (e < E) {
        int s = ei[e];
        int d = ei[E + e];
        int slot = rp[d] + atomicAdd(&tmp[d], 1);
        col[slot] = s;
    }
}

// g = dinv .* x  (row-wise pre-scale), f4-vectorized: N*8 f4 elements.
__global__ void k_prescale(const f4* __restrict__ x, const float* __restrict__ dinv,
                           f4* __restrict__ g, int N8) {
    int t = blockIdx.x * blockDim.x + threadIdx.x;
    if (t < N8) g[t] = dinv[t >> 3] * x[t];
}

// One hop on pre-scaled state: out[n] = scale(n) * (sum_{s in N(n)} g[s] + g[n])
// scale = dinv^2 (intermediate hops, keeps state pre-scaled) or dinv (final hop -> h).
// 32 lanes per row: j = lane>>3 in 0..3 strides edges, q = lane&7 picks the f4 chunk.
__global__ __launch_bounds__(256) void k_hop_gather(const int* __restrict__ rp,
                                                    const int* __restrict__ col,
                                                    const float* __restrict__ dinv,
                                                    const f4* __restrict__ gin,
                                                    f4* __restrict__ gout,
                                                    int N, int final_hop) {
    int t = blockIdx.x * blockDim.x + threadIdx.x;
    int n = t >> 5;
    if (n >= N) return;
    int lane = t & 31;
    int q = lane & 7;
    int j = lane >> 3;
    int e0 = rp[n], e1 = rp[n + 1];
    f4 acc = {0.f, 0.f, 0.f, 0.f};
    int e = e0 + j;
    for (; e + 4 < e1; e += 8) {
        int s0 = col[e];
        int s1 = col[e + 4];
        f4 a = gin[s0 * 8 + q];
        f4 b = gin[s1 * 8 + q];
        acc += a;
        acc += b;
    }
    if (e < e1) acc += gin[col[e] * 8 + q];
    // reduce across the 4 edge stripes (lanes differing in bits 3..4)
#pragma unroll
    for (int c = 0; c < 4; ++c) {
        float v = acc[c];
        v += __shfl_xor(v, 8);
        v += __shfl_xor(v, 16);
        acc[c] = v;
    }
    if (j == 0) {
        acc += gin[n * 8 + q];  // self-loop term
        float di = dinv[n];
        float sc = final_hop ? di : di * di;
        gout[n * 8 + q] = sc * acc;
    }
}

// out[n][o] = b[o] + sum_f h[n][f] * W[o][f]
__global__ __launch_bounds__(256) void k_linear(const float* __restrict__ h,
                                                const float* __restrict__ W,
                                                const float* __restrict__ b,
                                                float* __restrict__ out, int N) {
    __shared__ float Wl[F_OUT][F_IN + 1];
    __shared__ float hl[4][F_IN];
    int tid = threadIdx.x;
    for (int idx = tid; idx < F_OUT * F_IN; idx += 256) {
        Wl[idx >> 5][idx & 31] = W[idx];
    }
    int node0 = blockIdx.x * 4;
    if (tid < 4 * F_IN) {
        int n = tid >> 5, f = tid & 31;
        int node = node0 + n;
        hl[n][f] = (node < N) ? h[node * F_IN + f] : 0.0f;
    }
    __syncthreads();
    int n = tid >> 6;
    int o = tid & 63;
    int node = node0 + n;
    if (node < N) {
        float acc = b[o];
#pragma unroll
        for (int f = 0; f < F_IN; ++f) acc += hl[n][f] * Wl[o][f];
        out[node * F_OUT + o] = acc;
    }
}

extern "C" void kernel_launch(void* const* d_in, const int* in_sizes, int n_in,
                              void* d_out, int out_size, void* d_ws, size_t ws_size,
                              hipStream_t stream) {
    const float* x  = (const float*)d_in[0];
    const int*   ei = (const int*)d_in[1];   // [2,E] int32: src row then dst row
    const float* W  = (const float*)d_in[2];
    const float* b  = (const float*)d_in[3];
    float* out = (float*)d_out;

    const int N = in_sizes[0] / F_IN;
    const int E = in_sizes[1] / 2;
    const int nb = (N + SCAN_B - 1) / SCAN_B;

    // d_ws: deg(N) | tmp(N) | rp(N+1) | dinv(N) | bsum(nb) | hA(N*32 f)
    int*   deg  = (int*)d_ws;
    int*   tmp  = deg + N;
    int*   rp   = tmp + N;
    float* dinv = (float*)(rp + N + 1);
    int*   bsum = (int*)(dinv + N);
    float* hA   = (float*)(((uintptr_t)(bsum + nb) + 255) & ~(uintptr_t)255);

    // d_out scratch until k_linear: hB(N*32 f) | col(E int)  (N*64 f total available)
    float* hB  = out;
    int*   col = (int*)(out + N * F_IN);

    const int B = 256;
    dim3 blk(B);
    dim3 gN((N + B - 1) / B), gE((E + B - 1) / B);

    hipMemsetAsync(deg, 0, (size_t)N * sizeof(int), stream);
    hipMemsetAsync(tmp, 0, (size_t)N * sizeof(int), stream);

    // CSR build (col only)
    k_count_deg<<<gE, blk, 0, stream>>>(ei + E, deg, E);
    k_dinv<<<gN, blk, 0, stream>>>(deg, dinv, N);
    k_scan_block<<<dim3(nb), dim3(SCAN_B), 0, stream>>>(deg, rp, bsum, N);
    k_scan_bsums<<<dim3(1), dim3(512), 0, stream>>>(bsum, nb);
    k_scan_final<<<gN, blk, 0, stream>>>(rp, bsum, N);
    k_fill<<<gE, blk, 0, stream>>>(ei, rp, tmp, col, E);

    // pre-scale: g0 = dinv .* x  -> hB
    const int N8 = N * 8;
    k_prescale<<<dim3((N8 + B - 1) / B), blk, 0, stream>>>((const f4*)x, dinv, (f4*)hB, N8);

    // hops: hB -> hA -> hB -> hA (final lands in ws so k_linear can own d_out)
    dim3 gHop((N * 32 + B - 1) / B);
    k_hop_gather<<<gHop, blk, 0, stream>>>(rp, col, dinv, (const f4*)hB, (f4*)hA, N, 0);
    k_hop_gather<<<gHop, blk, 0, stream>>>(rp, col, dinv, (const f4*)hA, (f4*)hB, N, 0);
    k_hop_gather<<<gHop, blk, 0, stream>>>(rp, col, dinv, (const f4*)hB, (f4*)hA, N, 1);

    // linear: hA @ W^T + b -> out
    k_linear<<<dim3((N + 3) / 4), blk, 0, stream>>>(hA, W, b, out, N);
}

// Round 4
// 358.818 us; speedup vs baseline: 1.0328x; 1.0328x over previous
//
#include <hip/hip_runtime.h>

// SGConv: K=3 hops of \hat{A} x (symmetric gcn_norm w/ self-loops), then Linear.
// N=100000, E=1600000, F_in=32, F_out=64.
// Round 4: k_fill was 112us with 107MB WRITE (= E x 64B random line allocations).
// Fix: LDS-staged binning into 2048-node dst-buckets (coalesced ~84-edge runs),
// then a locality-preserving fill (cursor+col windows stay L2-resident).
// Hops: back to 8 lanes/row, unroll-4 for memory-level parallelism.

#define F_IN 32
#define F_OUT 64
#define SCAN_B 256
#define BKT_SHIFT 11                 // 2048 nodes per dst-bucket
#define EPB 4096                     // edges per k_bin block
#define MAXB 64                      // >= number of buckets (49 for N=100000)

typedef float f4 __attribute__((ext_vector_type(4)));

__global__ void k_count_deg(const int* __restrict__ dst, int* deg, int E) {
    int e = blockIdx.x * blockDim.x + threadIdx.x;
    if (e < E) atomicAdd(&deg[dst[e]], 1);
}

__global__ void k_dinv(const int* __restrict__ deg, float* __restrict__ dinv, int N) {
    int i = blockIdx.x * blockDim.x + threadIdx.x;
    if (i < N) dinv[i] = rsqrtf(1.0f + (float)deg[i]);  // +1 self-loop
}

__global__ __launch_bounds__(SCAN_B) void k_scan_block(const int* __restrict__ deg,
                                                       int* __restrict__ rp,
                                                       int* __restrict__ bsum, int N) {
    __shared__ int s[SCAN_B];
    int tid = threadIdx.x;
    int i = blockIdx.x * SCAN_B + tid;
    int v = (i < N) ? deg[i] : 0;
    s[tid] = v;
    __syncthreads();
    for (int off = 1; off < SCAN_B; off <<= 1) {
        int t = (tid >= off) ? s[tid - off] : 0;
        __syncthreads();
        s[tid] += t;
        __syncthreads();
    }
    if (i < N) rp[i + 1] = s[tid];
    if (tid == SCAN_B - 1) bsum[blockIdx.x] = s[tid];
}

__global__ __launch_bounds__(512) void k_scan_bsums(int* __restrict__ bsum, int nb) {
    __shared__ int s[512];
    int tid = threadIdx.x;
    int v = (tid < nb) ? bsum[tid] : 0;
    s[tid] = v;
    __syncthreads();
    for (int off = 1; off < 512; off <<= 1) {
        int t = (tid >= off) ? s[tid - off] : 0;
        __syncthreads();
        s[tid] += t;
        __syncthreads();
    }
    if (tid < nb) bsum[tid] = s[tid] - v;  // exclusive
}

__global__ void k_scan_final(int* __restrict__ rp, const int* __restrict__ bsum, int N) {
    int i = blockIdx.x * blockDim.x + threadIdx.x;
    if (i == 0) rp[0] = 0;
    if (i < N) rp[i + 1] += bsum[i >> 8];  // SCAN_B == 256
}

// cursor[i] = rp[i] (per-dst fill cursors); gcursor[b] = rp[b<<BKT_SHIFT] (bucket cursors)
__global__ void k_init_cursors(const int* __restrict__ rp, int* __restrict__ cursor,
                               int* __restrict__ gcursor, int N, int NBKT) {
    int i = blockIdx.x * blockDim.x + threadIdx.x;
    if (i < N) cursor[i] = rp[i];
    if (i < NBKT) {
        int nd = i << BKT_SHIFT;
        gcursor[i] = rp[nd < N ? nd : N];
    }
}

// Bin edges into dst-buckets of 2048 nodes. LDS-staged so global writes are
// coalesced runs (~EPB/49 ~ 84 edges = 672B per bucket per chunk).
__global__ __launch_bounds__(256) void k_bin(const int* __restrict__ ei,
                                             int* __restrict__ gcursor,
                                             uint2* __restrict__ binned, int E) {
    __shared__ uint2 stage[EPB];
    __shared__ int hist[MAXB], lscan[MAXB], lbase[MAXB], fcur[MAXB];
    int tid = threadIdx.x;
    int base = blockIdx.x * EPB;
    int cnt = E - base; if (cnt > EPB) cnt = EPB;

    if (tid < MAXB) hist[tid] = 0;
    __syncthreads();
    // phase 1: local histogram of dst-buckets
    for (int k = 0; k < EPB / 256; ++k) {
        int i = base + k * 256 + tid;
        if (i < E) atomicAdd(&hist[ei[E + i] >> BKT_SHIFT], 1);
    }
    __syncthreads();
    // phase 2: wave scan of MAXB counters + reserve global space per bucket
    if (tid < 64) {
        int c = (tid < MAXB) ? hist[tid] : 0;
        for (int off = 1; off < 64; off <<= 1) {
            int t = __shfl_up(c, off);
            if (tid >= off) c += t;
        }
        if (tid < MAXB) {
            int excl = c - hist[tid];
            lscan[tid] = excl;
            fcur[tid] = excl;
            lbase[tid] = hist[tid] ? atomicAdd(&gcursor[tid], hist[tid]) : 0;
        }
    }
    __syncthreads();
    // phase 3: reorder into LDS, bucket-grouped
    for (int k = 0; k < EPB / 256; ++k) {
        int i = base + k * 256 + tid;
        if (i < E) {
            unsigned s = (unsigned)ei[i];
            unsigned d = (unsigned)ei[E + i];
            int loc = atomicAdd(&fcur[d >> BKT_SHIFT], 1);
            stage[loc] = (uint2){s, d};
        }
    }
    __syncthreads();
    // phase 4: coalesced write-out
    for (int k = 0; k < EPB / 256; ++k) {
        int idx = k * 256 + tid;
        if (idx < cnt) {
            uint2 r = stage[idx];
            int b = r.y >> BKT_SHIFT;
            binned[lbase[b] + (idx - lscan[b])] = r;
        }
    }
}

// CSR fill from bucket-grouped edges: cursor + col accesses confined to
// one bucket's window (~8KB cursors, ~130KB col) -> L2-resident.
__global__ void k_fill2(const uint2* __restrict__ binned, int* cursor,
                        int* __restrict__ col, int E) {
    int i = blockIdx.x * blockDim.x + threadIdx.x;
    if (i < E) {
        uint2 r = binned[i];
        int slot = atomicAdd(&cursor[r.y], 1);
        col[slot] = r.x;
    }
}

// g = dinv .* x (row-wise pre-scale)
__global__ void k_prescale(const f4* __restrict__ x, const float* __restrict__ dinv,
                           f4* __restrict__ g, int N8) {
    int t = blockIdx.x * blockDim.x + threadIdx.x;
    if (t < N8) g[t] = dinv[t >> 3] * x[t];
}

// One hop on pre-scaled state: out[n] = sc * (sum_{s in N(n)} g[s] + g[n]),
// sc = dinv^2 (intermediate) or dinv (final). 8 lanes/row, unroll-4 MLP.
__global__ __launch_bounds__(256) void k_hop_gather(const int* __restrict__ rp,
                                                    const int* __restrict__ col,
                                                    const float* __restrict__ dinv,
                                                    const f4* __restrict__ gin,
                                                    f4* __restrict__ gout,
                                                    int N, int final_hop) {
    int t = blockIdx.x * blockDim.x + threadIdx.x;
    int n = t >> 3;
    if (n >= N) return;
    int q = t & 7;
    int e0 = rp[n], e1 = rp[n + 1];
    f4 a0 = gin[n * 8 + q];  // self-loop term
    f4 a1 = {0.f, 0.f, 0.f, 0.f};
    int e = e0;
    for (; e + 3 < e1; e += 4) {
        int s0 = col[e], s1 = col[e + 1], s2 = col[e + 2], s3 = col[e + 3];
        f4 h0 = gin[s0 * 8 + q];
        f4 h1 = gin[s1 * 8 + q];
        f4 h2 = gin[s2 * 8 + q];
        f4 h3 = gin[s3 * 8 + q];
        a0 += h0; a1 += h1; a0 += h2; a1 += h3;
    }
    for (; e < e1; ++e) a0 += gin[col[e] * 8 + q];
    float di = dinv[n];
    float sc = final_hop ? di : di * di;
    gout[n * 8 + q] = sc * (a0 + a1);
}

// out[n][o] = b[o] + sum_f h[n][f] * W[o][f]
__global__ __launch_bounds__(256) void k_linear(const float* __restrict__ h,
                                                const float* __restrict__ W,
                                                const float* __restrict__ b,
                                                float* __restrict__ out, int N) {
    __shared__ float Wl[F_OUT][F_IN + 1];
    __shared__ float hl[4][F_IN];
    int tid = threadIdx.x;
    for (int idx = tid; idx < F_OUT * F_IN; idx += 256) {
        Wl[idx >> 5][idx & 31] = W[idx];
    }
    int node0 = blockIdx.x * 4;
    if (tid < 4 * F_IN) {
        int n = tid >> 5, f = tid & 31;
        int node = node0 + n;
        hl[n][f] = (node < N) ? h[node * F_IN + f] : 0.0f;
    }
    __syncthreads();
    int n = tid >> 6;
    int o = tid & 63;
    int node = node0 + n;
    if (node < N) {
        float acc = b[o];
#pragma unroll
        for (int f = 0; f < F_IN; ++f) acc += hl[n][f] * Wl[o][f];
        out[node * F_OUT + o] = acc;
    }
}

extern "C" void kernel_launch(void* const* d_in, const int* in_sizes, int n_in,
                              void* d_out, int out_size, void* d_ws, size_t ws_size,
                              hipStream_t stream) {
    const float* x  = (const float*)d_in[0];
    const int*   ei = (const int*)d_in[1];   // [2,E] int32: src row then dst row
    const float* W  = (const float*)d_in[2];
    const float* b  = (const float*)d_in[3];
    float* out = (float*)d_out;

    const int N = in_sizes[0] / F_IN;
    const int E = in_sizes[1] / 2;
    const int nb = (N + SCAN_B - 1) / SCAN_B;
    const int NBKT = (N + (1 << BKT_SHIFT) - 1) >> BKT_SHIFT;  // 49

    // d_ws: deg(N) | rp(N+1) | dinv(N) | bsum(nb) | cursor(N) | gcursor(MAXB) | hA(N*32 f)
    int*   deg     = (int*)d_ws;
    int*   rp      = deg + N;
    float* dinv    = (float*)(rp + N + 1);
    int*   bsum    = (int*)(dinv + N);
    int*   cursor  = bsum + nb;
    int*   gcursor = cursor + N;
    float* hA      = (float*)(((uintptr_t)(gcursor + MAXB) + 255) & ~(uintptr_t)255);

    // d_out scratch: binned (E uint2 = 12.8MB) | col (E int = 6.4MB).
    // binned dies after k_fill2; its space is reused as hB. k_linear finally owns d_out.
    uint2* binned = (uint2*)d_out;
    float* hB     = out;                       // aliases binned (sequenced after fill2)
    int*   col    = (int*)(out + (size_t)N * F_IN);

    const int B = 256;
    dim3 blk(B);
    dim3 gN((N + B - 1) / B), gE((E + B - 1) / B);

    hipMemsetAsync(deg, 0, (size_t)N * sizeof(int), stream);

    // degree + dinv + row pointers
    k_count_deg<<<gE, blk, 0, stream>>>(ei + E, deg, E);
    k_dinv<<<gN, blk, 0, stream>>>(deg, dinv, N);
    k_scan_block<<<dim3(nb), dim3(SCAN_B), 0, stream>>>(deg, rp, bsum, N);
    k_scan_bsums<<<dim3(1), dim3(512), 0, stream>>>(bsum, nb);
    k_scan_final<<<gN, blk, 0, stream>>>(rp, bsum, N);
    k_init_cursors<<<gN, blk, 0, stream>>>(rp, cursor, gcursor, N, NBKT);

    // binning + locality-preserving CSR fill
    k_bin<<<dim3((E + EPB - 1) / EPB), blk, 0, stream>>>(ei, gcursor, binned, E);
    k_fill2<<<gE, blk, 0, stream>>>(binned, cursor, col, E);

    // pre-scale: g0 = dinv .* x -> hB
    const int N8 = N * 8;
    k_prescale<<<dim3((N8 + B - 1) / B), blk, 0, stream>>>((const f4*)x, dinv, (f4*)hB, N8);

    // hops: hB -> hA -> hB -> hA
    dim3 gHop(((size_t)N * 8 + B - 1) / B);
    k_hop_gather<<<gHop, blk, 0, stream>>>(rp, col, dinv, (const f4*)hB, (f4*)hA, N, 0);
    k_hop_gather<<<gHop, blk, 0, stream>>>(rp, col, dinv, (const f4*)hA, (f4*)hB, N, 0);
    k_hop_gather<<<gHop, blk, 0, stream>>>(rp, col, dinv, (const f4*)hB, (f4*)hA, N, 1);

    // linear: hA @ W^T + b -> out
    k_linear<<<dim3((N + 3) / 4), blk, 0, stream>>>(hA, W, b, out, N);
}

// Round 5
// 357.526 us; speedup vs baseline: 1.0365x; 1.0036x over previous
//
#include <hip/hip_runtime.h>

// SGConv: K=3 hops of \hat{A} x (symmetric gcn_norm w/ self-loops), then Linear.
// N=100000, E=1600000, F_in=32, F_out=64.
// Round 5: k_count_deg was 65us / 50MB WRITE (random device atomics write through
// to HBM). Proven fix pattern from k_fill2: do the atomics on bucket-grouped data
// so they stay in an 8KB L2-resident window. Pipeline: bucket histogram (LDS) ->
// bucket scan -> k_bin -> k_count_deg2(binned) -> dinv/rp scan -> k_fill2 -> hops.

#define F_IN 32
#define F_OUT 64
#define SCAN_B 256
#define BKT_SHIFT 11                 // 2048 nodes per dst-bucket
#define EPB 4096                     // edges per binning/histogram block
#define MAXB 64                      // >= number of buckets (49 for N=100000)

typedef float f4 __attribute__((ext_vector_type(4)));

// Per-block LDS histogram of dst-buckets -> 64 global atomics per block.
__global__ __launch_bounds__(256) void k_bucket_hist(const int* __restrict__ dst,
                                                     int* __restrict__ bcount, int E) {
    __shared__ int h[MAXB];
    int tid = threadIdx.x;
    if (tid < MAXB) h[tid] = 0;
    __syncthreads();
    int base = blockIdx.x * EPB;
    for (int k = 0; k < EPB / 256; ++k) {
        int i = base + k * 256 + tid;
        if (i < E) atomicAdd(&h[dst[i] >> BKT_SHIFT], 1);
    }
    __syncthreads();
    if (tid < MAXB && h[tid]) atomicAdd(&bcount[tid], h[tid]);
}

// One wave: exclusive scan of the 64 bucket counts -> k_bin's global cursors.
__global__ void k_scan_buckets(const int* __restrict__ bcount, int* __restrict__ gcursor) {
    int tid = threadIdx.x;  // launched with 64 threads
    int c = bcount[tid];
    int inc = c;
    for (int off = 1; off < 64; off <<= 1) {
        int t = __shfl_up(inc, off);
        if (tid >= off) inc += t;
    }
    gcursor[tid] = inc - c;  // exclusive
}

// Bin edges into dst-buckets of 2048 nodes. LDS-staged so global writes are
// coalesced runs (~EPB/49 ~ 84 edges per bucket per chunk).
__global__ __launch_bounds__(256) void k_bin(const int* __restrict__ ei,
                                             int* __restrict__ gcursor,
                                             uint2* __restrict__ binned, int E) {
    __shared__ uint2 stage[EPB];
    __shared__ int hist[MAXB], lscan[MAXB], lbase[MAXB], fcur[MAXB];
    int tid = threadIdx.x;
    int base = blockIdx.x * EPB;
    int cnt = E - base; if (cnt > EPB) cnt = EPB;

    if (tid < MAXB) hist[tid] = 0;
    __syncthreads();
    for (int k = 0; k < EPB / 256; ++k) {
        int i = base + k * 256 + tid;
        if (i < E) atomicAdd(&hist[ei[E + i] >> BKT_SHIFT], 1);
    }
    __syncthreads();
    if (tid < 64) {
        int c = (tid < MAXB) ? hist[tid] : 0;
        for (int off = 1; off < 64; off <<= 1) {
            int t = __shfl_up(c, off);
            if (tid >= off) c += t;
        }
        if (tid < MAXB) {
            int excl = c - hist[tid];
            lscan[tid] = excl;
            fcur[tid] = excl;
            lbase[tid] = hist[tid] ? atomicAdd(&gcursor[tid], hist[tid]) : 0;
        }
    }
    __syncthreads();
    for (int k = 0; k < EPB / 256; ++k) {
        int i = base + k * 256 + tid;
        if (i < E) {
            unsigned s = (unsigned)ei[i];
            unsigned d = (unsigned)ei[E + i];
            int loc = atomicAdd(&fcur[d >> BKT_SHIFT], 1);
            stage[loc] = (uint2){s, d};
        }
    }
    __syncthreads();
    for (int k = 0; k < EPB / 256; ++k) {
        int idx = k * 256 + tid;
        if (idx < cnt) {
            uint2 r = stage[idx];
            int b = r.y >> BKT_SHIFT;
            binned[lbase[b] + (idx - lscan[b])] = r;
        }
    }
}

// Degree count on bucket-grouped edges: atomics confined to an 8KB window.
__global__ void k_count_deg2(const uint2* __restrict__ binned, int* deg, int E) {
    int i = blockIdx.x * blockDim.x + threadIdx.x;
    if (i < E) atomicAdd(&deg[binned[i].y], 1);
}

__global__ void k_dinv(const int* __restrict__ deg, float* __restrict__ dinv, int N) {
    int i = blockIdx.x * blockDim.x + threadIdx.x;
    if (i < N) dinv[i] = rsqrtf(1.0f + (float)deg[i]);  // +1 self-loop
}

__global__ __launch_bounds__(SCAN_B) void k_scan_block(const int* __restrict__ deg,
                                                       int* __restrict__ rp,
                                                       int* __restrict__ bsum, int N) {
    __shared__ int s[SCAN_B];
    int tid = threadIdx.x;
    int i = blockIdx.x * SCAN_B + tid;
    int v = (i < N) ? deg[i] : 0;
    s[tid] = v;
    __syncthreads();
    for (int off = 1; off < SCAN_B; off <<= 1) {
        int t = (tid >= off) ? s[tid - off] : 0;
        __syncthreads();
        s[tid] += t;
        __syncthreads();
    }
    if (i < N) rp[i + 1] = s[tid];
    if (tid == SCAN_B - 1) bsum[blockIdx.x] = s[tid];
}

__global__ __launch_bounds__(512) void k_scan_bsums(int* __restrict__ bsum, int nb) {
    __shared__ int s[512];
    int tid = threadIdx.x;
    int v = (tid < nb) ? bsum[tid] : 0;
    s[tid] = v;
    __syncthreads();
    for (int off = 1; off < 512; off <<= 1) {
        int t = (tid >= off) ? s[tid - off] : 0;
        __syncthreads();
        s[tid] += t;
        __syncthreads();
    }
    if (tid < nb) bsum[tid] = s[tid] - v;  // exclusive
}

__global__ void k_scan_final(int* __restrict__ rp, const int* __restrict__ bsum, int N) {
    int i = blockIdx.x * blockDim.x + threadIdx.x;
    if (i == 0) rp[0] = 0;
    if (i < N) rp[i + 1] += bsum[i >> 8];  // SCAN_B == 256
}

__global__ void k_init_cursor(const int* __restrict__ rp, int* __restrict__ cursor, int N) {
    int i = blockIdx.x * blockDim.x + threadIdx.x;
    if (i < N) cursor[i] = rp[i];
}

// CSR fill from bucket-grouped edges (cursor + col windows L2-resident).
__global__ void k_fill2(const uint2* __restrict__ binned, int* cursor,
                        int* __restrict__ col, int E) {
    int i = blockIdx.x * blockDim.x + threadIdx.x;
    if (i < E) {
        uint2 r = binned[i];
        int slot = atomicAdd(&cursor[r.y], 1);
        col[slot] = r.x;
    }
}

// g = dinv .* x (row-wise pre-scale)
__global__ void k_prescale(const f4* __restrict__ x, const float* __restrict__ dinv,
                           f4* __restrict__ g, int N8) {
    int t = blockIdx.x * blockDim.x + threadIdx.x;
    if (t < N8) g[t] = dinv[t >> 3] * x[t];
}

// One hop on pre-scaled state: out[n] = sc * (sum_{s in N(n)} g[s] + g[n]),
// sc = dinv^2 (intermediate) or dinv (final). 8 lanes/row, unroll-4 MLP.
__global__ __launch_bounds__(256) void k_hop_gather(const int* __restrict__ rp,
                                                    const int* __restrict__ col,
                                                    const float* __restrict__ dinv,
                                                    const f4* __restrict__ gin,
                                                    f4* __restrict__ gout,
                                                    int N, int final_hop) {
    int t = blockIdx.x * blockDim.x + threadIdx.x;
    int n = t >> 3;
    if (n >= N) return;
    int q = t & 7;
    int e0 = rp[n], e1 = rp[n + 1];
    f4 a0 = gin[n * 8 + q];  // self-loop term
    f4 a1 = {0.f, 0.f, 0.f, 0.f};
    int e = e0;
    for (; e + 3 < e1; e += 4) {
        int s0 = col[e], s1 = col[e + 1], s2 = col[e + 2], s3 = col[e + 3];
        f4 h0 = gin[s0 * 8 + q];
        f4 h1 = gin[s1 * 8 + q];
        f4 h2 = gin[s2 * 8 + q];
        f4 h3 = gin[s3 * 8 + q];
        a0 += h0; a1 += h1; a0 += h2; a1 += h3;
    }
    for (; e < e1; ++e) a0 += gin[col[e] * 8 + q];
    float di = dinv[n];
    float sc = final_hop ? di : di * di;
    gout[n * 8 + q] = sc * (a0 + a1);
}

// out[n][o] = b[o] + sum_f h[n][f] * W[o][f]
__global__ __launch_bounds__(256) void k_linear(const float* __restrict__ h,
                                                const float* __restrict__ W,
                                                const float* __restrict__ b,
                                                float* __restrict__ out, int N) {
    __shared__ float Wl[F_OUT][F_IN + 1];
    __shared__ float hl[4][F_IN];
    int tid = threadIdx.x;
    for (int idx = tid; idx < F_OUT * F_IN; idx += 256) {
        Wl[idx >> 5][idx & 31] = W[idx];
    }
    int node0 = blockIdx.x * 4;
    if (tid < 4 * F_IN) {
        int n = tid >> 5, f = tid & 31;
        int node = node0 + n;
        hl[n][f] = (node < N) ? h[node * F_IN + f] : 0.0f;
    }
    __syncthreads();
    int n = tid >> 6;
    int o = tid & 63;
    int node = node0 + n;
    if (node < N) {
        float acc = b[o];
#pragma unroll
        for (int f = 0; f < F_IN; ++f) acc += hl[n][f] * Wl[o][f];
        out[node * F_OUT + o] = acc;
    }
}

extern "C" void kernel_launch(void* const* d_in, const int* in_sizes, int n_in,
                              void* d_out, int out_size, void* d_ws, size_t ws_size,
                              hipStream_t stream) {
    const float* x  = (const float*)d_in[0];
    const int*   ei = (const int*)d_in[1];   // [2,E] int32: src row then dst row
    const float* W  = (const float*)d_in[2];
    const float* b  = (const float*)d_in[3];
    float* out = (float*)d_out;

    const int N = in_sizes[0] / F_IN;
    const int E = in_sizes[1] / 2;
    const int nb = (N + SCAN_B - 1) / SCAN_B;

    // d_ws: deg(N) | bcount(MAXB) | rp(N+1) | dinv(N) | bsum(nb) | cursor(N) |
    //       gcursor(MAXB) | hA(N*32 f)
    int*   deg     = (int*)d_ws;
    int*   bcount  = deg + N;
    int*   rp      = bcount + MAXB;
    float* dinv    = (float*)(rp + N + 1);
    int*   bsum    = (int*)(dinv + N);
    int*   cursor  = bsum + nb;
    int*   gcursor = cursor + N;
    float* hA      = (float*)(((uintptr_t)(gcursor + MAXB) + 255) & ~(uintptr_t)255);

    // d_out scratch: binned (E uint2 = 12.8MB) | col (E int = 6.4MB).
    // binned dies after k_fill2; its space is reused as hB. k_linear finally owns d_out.
    uint2* binned = (uint2*)d_out;
    float* hB     = out;                       // aliases binned (sequenced after fill2)
    int*   col    = (int*)(out + (size_t)N * F_IN);

    const int B = 256;
    dim3 blk(B);
    dim3 gN((N + B - 1) / B), gE((E + B - 1) / B);
    dim3 gEPB((E + EPB - 1) / EPB);

    hipMemsetAsync(deg, 0, ((size_t)N + MAXB) * sizeof(int), stream);  // deg + bcount

    // bucket histogram + scan -> bin cursors; bin edges (coalesced writes)
    k_bucket_hist<<<gEPB, blk, 0, stream>>>(ei + E, bcount, E);
    k_scan_buckets<<<dim3(1), dim3(64), 0, stream>>>(bcount, gcursor);
    k_bin<<<gEPB, blk, 0, stream>>>(ei, gcursor, binned, E);

    // degree on bucket-grouped edges (L2-windowed atomics), then dinv + rp
    k_count_deg2<<<gE, blk, 0, stream>>>(binned, deg, E);
    k_dinv<<<gN, blk, 0, stream>>>(deg, dinv, N);
    k_scan_block<<<dim3(nb), dim3(SCAN_B), 0, stream>>>(deg, rp, bsum, N);
    k_scan_bsums<<<dim3(1), dim3(512), 0, stream>>>(bsum, nb);
    k_scan_final<<<gN, blk, 0, stream>>>(rp, bsum, N);
    k_init_cursor<<<gN, blk, 0, stream>>>(rp, cursor, N);

    // CSR fill (L2-windowed)
    k_fill2<<<gE, blk, 0, stream>>>(binned, cursor, col, E);

    // pre-scale: g0 = dinv .* x -> hB
    const int N8 = N * 8;
    k_prescale<<<dim3((N8 + B - 1) / B), blk, 0, stream>>>((const f4*)x, dinv, (f4*)hB, N8);

    // hops: hB -> hA -> hB -> hA
    dim3 gHop(((size_t)N * 8 + B - 1) / B);
    k_hop_gather<<<gHop, blk, 0, stream>>>(rp, col, dinv, (const f4*)hB, (f4*)hA, N, 0);
    k_hop_gather<<<gHop, blk, 0, stream>>>(rp, col, dinv, (const f4*)hA, (f4*)hB, N, 0);
    k_hop_gather<<<gHop, blk, 0, stream>>>(rp, col, dinv, (const f4*)hB, (f4*)hA, N, 1);

    // linear: hA @ W^T + b -> out
    k_linear<<<dim3((N + 3) / 4), blk, 0, stream>>>(hA, W, b, out, N);
}

// Round 6
// 280.076 us; speedup vs baseline: 1.3231x; 1.2765x over previous
//
#include <hip/hip_runtime.h>

// SGConv: K=3 hops of \hat{A} x (symmetric gcn_norm w/ self-loops), then Linear.
// N=100000, E=1600000, F_in=32, F_out=64.
// Round 6: k_fill2 wrote 77MB (48B/edge) because each bucket's col lines were
// dirtied by ~128 blocks spread across 8 non-coherent XCD L2s -> duplicated
// partial-line write-back. Fix: 1024-node buckets, ONE workgroup per bucket
// does hist+scan+deg/dinv/rp+col scatter entirely via LDS (k_fill3) -> every
// output line owned by one CU/XCD. Replaces 6 kernels (count_deg2, dinv,
// 3-kernel rp scan, init_cursor, fill2) with one.

#define F_IN 32
#define F_OUT 64
#define BKT_SHIFT 10                 // 1024 nodes per dst-bucket
#define BKT (1 << BKT_SHIFT)
#define EPB 4096                     // edges per binning/histogram block
#define MAXB 128                     // >= number of buckets (98 for N=100000)

typedef float f4 __attribute__((ext_vector_type(4)));

// Per-block LDS histogram of dst-buckets -> MAXB global atomics per block.
__global__ __launch_bounds__(256) void k_bucket_hist(const int* __restrict__ dst,
                                                     int* __restrict__ bcount, int E) {
    __shared__ int h[MAXB];
    int tid = threadIdx.x;
    if (tid < MAXB) h[tid] = 0;
    __syncthreads();
    int base = blockIdx.x * EPB;
    for (int k = 0; k < EPB / 256; ++k) {
        int i = base + k * 256 + tid;
        if (i < E) atomicAdd(&h[dst[i] >> BKT_SHIFT], 1);
    }
    __syncthreads();
    if (tid < MAXB && h[tid]) atomicAdd(&bcount[tid], h[tid]);
}

// One block (MAXB threads): exclusive scan of bucket counts.
// colbase[b] = stable bucket base in col/binned; colbase[MAXB] = E.
// gcursor[b] = mutable copy for k_bin's space reservation.
__global__ __launch_bounds__(MAXB) void k_scan_buckets(const int* __restrict__ bcount,
                                                       int* __restrict__ colbase,
                                                       int* __restrict__ gcursor) {
    __shared__ int sc[MAXB];
    int tid = threadIdx.x;
    int c = bcount[tid];
    sc[tid] = c;
    __syncthreads();
    for (int off = 1; off < MAXB; off <<= 1) {
        int t = (tid >= off) ? sc[tid - off] : 0;
        __syncthreads();
        sc[tid] += t;
        __syncthreads();
    }
    int excl = sc[tid] - c;
    colbase[tid] = excl;
    gcursor[tid] = excl;
    if (tid == MAXB - 1) colbase[MAXB] = sc[tid];
}

// Bin edges into dst-buckets. LDS-staged so global writes are coalesced runs.
__global__ __launch_bounds__(256) void k_bin(const int* __restrict__ ei,
                                             int* __restrict__ gcursor,
                                             uint2* __restrict__ binned, int E) {
    __shared__ uint2 stage[EPB];
    __shared__ int hist[MAXB], lscan[MAXB], lbase[MAXB], fcur[MAXB], sc[MAXB];
    int tid = threadIdx.x;
    int base = blockIdx.x * EPB;
    int cnt = E - base; if (cnt > EPB) cnt = EPB;

    if (tid < MAXB) hist[tid] = 0;
    __syncthreads();
    for (int k = 0; k < EPB / 256; ++k) {
        int i = base + k * 256 + tid;
        if (i < E) atomicAdd(&hist[ei[E + i] >> BKT_SHIFT], 1);
    }
    __syncthreads();
    if (tid < MAXB) sc[tid] = hist[tid];
    __syncthreads();
    for (int off = 1; off < MAXB; off <<= 1) {
        int t = (tid < MAXB && tid >= off) ? sc[tid - off] : 0;
        __syncthreads();
        if (tid < MAXB) sc[tid] += t;
        __syncthreads();
    }
    if (tid < MAXB) {
        int excl = sc[tid] - hist[tid];
        lscan[tid] = excl;
        fcur[tid] = excl;
        lbase[tid] = hist[tid] ? atomicAdd(&gcursor[tid], hist[tid]) : 0;
    }
    __syncthreads();
    for (int k = 0; k < EPB / 256; ++k) {
        int i = base + k * 256 + tid;
        if (i < E) {
            unsigned s = (unsigned)ei[i];
            unsigned d = (unsigned)ei[E + i];
            int loc = atomicAdd(&fcur[d >> BKT_SHIFT], 1);
            stage[loc] = (uint2){s, d};
        }
    }
    __syncthreads();
    for (int k = 0; k < EPB / 256; ++k) {
        int idx = k * 256 + tid;
        if (idx < cnt) {
            uint2 r = stage[idx];
            int b = r.y >> BKT_SHIFT;
            binned[lbase[b] + (idx - lscan[b])] = r;
        }
    }
}

// One workgroup per bucket: LDS hist of 1024 local dst -> scan -> writes
// dinv + rp (coalesced), then scatters col via LDS cursors. No global atomics;
// every output line is written by exactly one CU (one XCD's L2).
__global__ __launch_bounds__(256) void k_fill3(const uint2* __restrict__ binned,
                                               const int* __restrict__ colbase,
                                               float* __restrict__ dinv,
                                               int* __restrict__ rp,
                                               int* __restrict__ col, int N) {
    __shared__ int h[BKT];
    __shared__ int ws[256];
    int tid = threadIdx.x;
    int b = blockIdx.x;
    int base_node = b << BKT_SHIFT;
    int cbase = colbase[b];
    int cend  = colbase[b + 1];

    for (int i = tid; i < BKT; i += 256) h[i] = 0;
    __syncthreads();
    for (int e = cbase + tid; e < cend; e += 256)
        atomicAdd(&h[binned[e].y & (BKT - 1)], 1);
    __syncthreads();

    // scan: each thread owns 4 consecutive counters
    int a0 = h[4 * tid], a1 = h[4 * tid + 1], a2 = h[4 * tid + 2], a3 = h[4 * tid + 3];
    int s = a0 + a1 + a2 + a3;
    ws[tid] = s;
    __syncthreads();
    for (int off = 1; off < 256; off <<= 1) {
        int t = (tid >= off) ? ws[tid - off] : 0;
        __syncthreads();
        ws[tid] += t;
        __syncthreads();
    }
    int excl = ws[tid] - s;

    // deg -> dinv, global rp (coalesced), cursors back into h
    int i0 = 4 * tid;
#pragma unroll
    for (int k = 0; k < 4; ++k) {
        int node = base_node + i0 + k;
        int deg = (k == 0) ? a0 : (k == 1) ? a1 : (k == 2) ? a2 : a3;
        int e_here = excl;
        excl += deg;
        if (node < N) {
            dinv[node] = rsqrtf(1.0f + (float)deg);
            rp[node + 1] = cbase + e_here + deg;  // inclusive
        }
        h[i0 + k] = e_here;  // exclusive -> scatter cursor
    }
    if (b == 0 && tid == 0) rp[0] = 0;
    __syncthreads();

    // scatter: col window [cbase, cend) owned entirely by this workgroup
    for (int e = cbase + tid; e < cend; e += 256) {
        uint2 r = binned[e];
        int slot = cbase + atomicAdd(&h[r.y & (BKT - 1)], 1);
        col[slot] = r.x;
    }
}

// g = dinv .* x (row-wise pre-scale)
__global__ void k_prescale(const f4* __restrict__ x, const float* __restrict__ dinv,
                           f4* __restrict__ g, int N8) {
    int t = blockIdx.x * blockDim.x + threadIdx.x;
    if (t < N8) g[t] = dinv[t >> 3] * x[t];
}

// One hop on pre-scaled state: out[n] = sc * (sum_{s in N(n)} g[s] + g[n]),
// sc = dinv^2 (intermediate) or dinv (final). 8 lanes/row, unroll-4 MLP.
__global__ __launch_bounds__(256) void k_hop_gather(const int* __restrict__ rp,
                                                    const int* __restrict__ col,
                                                    const float* __restrict__ dinv,
                                                    const f4* __restrict__ gin,
                                                    f4* __restrict__ gout,
                                                    int N, int final_hop) {
    int t = blockIdx.x * blockDim.x + threadIdx.x;
    int n = t >> 3;
    if (n >= N) return;
    int q = t & 7;
    int e0 = rp[n], e1 = rp[n + 1];
    f4 a0 = gin[n * 8 + q];  // self-loop term
    f4 a1 = {0.f, 0.f, 0.f, 0.f};
    int e = e0;
    for (; e + 3 < e1; e += 4) {
        int s0 = col[e], s1 = col[e + 1], s2 = col[e + 2], s3 = col[e + 3];
        f4 h0 = gin[s0 * 8 + q];
        f4 h1 = gin[s1 * 8 + q];
        f4 h2 = gin[s2 * 8 + q];
        f4 h3 = gin[s3 * 8 + q];
        a0 += h0; a1 += h1; a0 += h2; a1 += h3;
    }
    for (; e < e1; ++e) a0 += gin[col[e] * 8 + q];
    float di = dinv[n];
    float sc = final_hop ? di : di * di;
    gout[n * 8 + q] = sc * (a0 + a1);
}

// out[n][o] = b[o] + sum_f h[n][f] * W[o][f]
__global__ __launch_bounds__(256) void k_linear(const float* __restrict__ h,
                                                const float* __restrict__ W,
                                                const float* __restrict__ b,
                                                float* __restrict__ out, int N) {
    __shared__ float Wl[F_OUT][F_IN + 1];
    __shared__ float hl[4][F_IN];
    int tid = threadIdx.x;
    for (int idx = tid; idx < F_OUT * F_IN; idx += 256) {
        Wl[idx >> 5][idx & 31] = W[idx];
    }
    int node0 = blockIdx.x * 4;
    if (tid < 4 * F_IN) {
        int n = tid >> 5, f = tid & 31;
        int node = node0 + n;
        hl[n][f] = (node < N) ? h[node * F_IN + f] : 0.0f;
    }
    __syncthreads();
    int n = tid >> 6;
    int o = tid & 63;
    int node = node0 + n;
    if (node < N) {
        float acc = b[o];
#pragma unroll
        for (int f = 0; f < F_IN; ++f) acc += hl[n][f] * Wl[o][f];
        out[node * F_OUT + o] = acc;
    }
}

extern "C" void kernel_launch(void* const* d_in, const int* in_sizes, int n_in,
                              void* d_out, int out_size, void* d_ws, size_t ws_size,
                              hipStream_t stream) {
    const float* x  = (const float*)d_in[0];
    const int*   ei = (const int*)d_in[1];   // [2,E] int32: src row then dst row
    const float* W  = (const float*)d_in[2];
    const float* b  = (const float*)d_in[3];
    float* out = (float*)d_out;

    const int N = in_sizes[0] / F_IN;
    const int E = in_sizes[1] / 2;
    const int NBKT = (N + BKT - 1) >> BKT_SHIFT;  // 98

    // d_ws: bcount(MAXB) | colbase(MAXB+1) | gcursor(MAXB) | rp(N+1) | dinv(N) | hA(N*32 f)
    int*   bcount  = (int*)d_ws;
    int*   colbase = bcount + MAXB;
    int*   gcursor = colbase + MAXB + 1;
    int*   rp      = gcursor + MAXB;
    float* dinv    = (float*)(rp + N + 1);
    float* hA      = (float*)(((uintptr_t)(dinv + N) + 255) & ~(uintptr_t)255);

    // d_out scratch: binned (E uint2 = 12.8MB) | col (E int = 6.4MB).
    // binned dies after k_fill3; its space is reused as hB. k_linear finally owns d_out.
    uint2* binned = (uint2*)d_out;
    float* hB     = out;                       // aliases binned (sequenced after fill3)
    int*   col    = (int*)(out + (size_t)N * F_IN);

    const int B = 256;
    dim3 blk(B);
    dim3 gEPB((E + EPB - 1) / EPB);

    hipMemsetAsync(bcount, 0, MAXB * sizeof(int), stream);

    // bucket histogram + scan -> bases/cursors; bin edges (coalesced writes)
    k_bucket_hist<<<gEPB, blk, 0, stream>>>(ei + E, bcount, E);
    k_scan_buckets<<<dim3(1), dim3(MAXB), 0, stream>>>(bcount, colbase, gcursor);
    k_bin<<<gEPB, blk, 0, stream>>>(ei, gcursor, binned, E);

    // per-bucket counting sort: deg/dinv/rp/col, all XCD-local writes
    k_fill3<<<dim3(NBKT), blk, 0, stream>>>(binned, colbase, dinv, rp, col, N);

    // pre-scale: g0 = dinv .* x -> hB
    const int N8 = N * 8;
    k_prescale<<<dim3((N8 + B - 1) / B), blk, 0, stream>>>((const f4*)x, dinv, (f4*)hB, N8);

    // hops: hB -> hA -> hB -> hA
    dim3 gHop(((size_t)N * 8 + B - 1) / B);
    k_hop_gather<<<gHop, blk, 0, stream>>>(rp, col, dinv, (const f4*)hB, (f4*)hA, N, 0);
    k_hop_gather<<<gHop, blk, 0, stream>>>(rp, col, dinv, (const f4*)hA, (f4*)hB, N, 0);
    k_hop_gather<<<gHop, blk, 0, stream>>>(rp, col, dinv, (const f4*)hB, (f4*)hA, N, 1);

    // linear: hA @ W^T + b -> out
    k_linear<<<dim3((N + 3) / 4), blk, 0, stream>>>(hA, W, b, out, N);
}

// Round 7
// 252.975 us; speedup vs baseline: 1.4648x; 1.1071x over previous
//
#include <hip/hip_runtime.h>

// SGConv: K=3 hops of \hat{A} x (symmetric gcn_norm w/ self-loops), then Linear.
// N=100000, E=1600000, F_in=32, F_out=64.
// Round 7: k_fill3 was 44us at 229GB/s -> parallelism-bound (98 blocks x 256thr,
// 64-iter serial loops), not memory-bound. Fix: 512-node buckets (196 blocks x
// 512 thr, 16-iter loops, shfl scan) + pack binned records to 4B (s<<9|dlocal,
// src<2^17) halving k_bin WRITE and k_fill3 FETCH. Ownership invariant kept:
// each col/rp/dinv line written by exactly one workgroup.

#define F_IN 32
#define F_OUT 64
#define BKT_SHIFT 9                  // 512 nodes per dst-bucket
#define BKT (1 << BKT_SHIFT)
#define EPB 4096                     // edges per binning/histogram block
#define MAXB 256                     // >= number of buckets (196 for N=100000)

typedef float f4 __attribute__((ext_vector_type(4)));

// Per-block LDS histogram of dst-buckets -> MAXB global atomics per block.
__global__ __launch_bounds__(256) void k_bucket_hist(const int* __restrict__ dst,
                                                     int* __restrict__ bcount, int E) {
    __shared__ int h[MAXB];
    int tid = threadIdx.x;
    h[tid] = 0;
    __syncthreads();
    int base = blockIdx.x * EPB;
    for (int k = 0; k < EPB / 256; ++k) {
        int i = base + k * 256 + tid;
        if (i < E) atomicAdd(&h[dst[i] >> BKT_SHIFT], 1);
    }
    __syncthreads();
    if (h[tid]) atomicAdd(&bcount[tid], h[tid]);
}

// One block (MAXB threads): exclusive scan of bucket counts.
__global__ __launch_bounds__(MAXB) void k_scan_buckets(const int* __restrict__ bcount,
                                                       int* __restrict__ colbase,
                                                       int* __restrict__ gcursor) {
    __shared__ int sc[MAXB];
    int tid = threadIdx.x;
    int c = bcount[tid];
    sc[tid] = c;
    __syncthreads();
    for (int off = 1; off < MAXB; off <<= 1) {
        int t = (tid >= off) ? sc[tid - off] : 0;
        __syncthreads();
        sc[tid] += t;
        __syncthreads();
    }
    int excl = sc[tid] - c;
    colbase[tid] = excl;
    gcursor[tid] = excl;
    if (tid == MAXB - 1) colbase[MAXB] = sc[tid];
}

// Bin edges into dst-buckets; records packed to 4B: (src << 9) | (dst & 511).
__global__ __launch_bounds__(256) void k_bin(const int* __restrict__ ei,
                                             int* __restrict__ gcursor,
                                             unsigned* __restrict__ binned, int E) {
    __shared__ unsigned stage[EPB];          // 16 KB
    __shared__ unsigned char bid[EPB];       // 4 KB: bucket id per stage slot
    __shared__ int hist[MAXB], lscan[MAXB], lbase[MAXB], fcur[MAXB], sc[MAXB];
    int tid = threadIdx.x;
    int base = blockIdx.x * EPB;
    int cnt = E - base; if (cnt > EPB) cnt = EPB;

    hist[tid] = 0;
    __syncthreads();
    for (int k = 0; k < EPB / 256; ++k) {
        int i = base + k * 256 + tid;
        if (i < E) atomicAdd(&hist[ei[E + i] >> BKT_SHIFT], 1);
    }
    __syncthreads();
    sc[tid] = hist[tid];
    __syncthreads();
    for (int off = 1; off < MAXB; off <<= 1) {
        int t = (tid >= off) ? sc[tid - off] : 0;
        __syncthreads();
        sc[tid] += t;
        __syncthreads();
    }
    {
        int excl = sc[tid] - hist[tid];
        lscan[tid] = excl;
        fcur[tid] = excl;
        lbase[tid] = hist[tid] ? atomicAdd(&gcursor[tid], hist[tid]) : 0;
    }
    __syncthreads();
    for (int k = 0; k < EPB / 256; ++k) {
        int i = base + k * 256 + tid;
        if (i < E) {
            unsigned s = (unsigned)ei[i];
            unsigned d = (unsigned)ei[E + i];
            int b = d >> BKT_SHIFT;
            int loc = atomicAdd(&fcur[b], 1);
            stage[loc] = (s << BKT_SHIFT) | (d & (BKT - 1));
            bid[loc] = (unsigned char)b;
        }
    }
    __syncthreads();
    for (int k = 0; k < EPB / 256; ++k) {
        int idx = k * 256 + tid;
        if (idx < cnt) {
            int b = bid[idx];
            binned[lbase[b] + (idx - lscan[b])] = stage[idx];
        }
    }
}

// One workgroup (512 thr) per 512-node bucket: LDS hist -> shfl scan ->
// dinv/rp (coalesced) -> col scatter via LDS cursors. No global atomics;
// every output line owned by one CU/XCD.
__global__ __launch_bounds__(512) void k_fill3(const unsigned* __restrict__ binned,
                                               const int* __restrict__ colbase,
                                               float* __restrict__ dinv,
                                               int* __restrict__ rp,
                                               int* __restrict__ col, int N) {
    __shared__ int h[BKT];
    __shared__ int wsum[8];
    int tid = threadIdx.x;
    int b = blockIdx.x;
    int base_node = b << BKT_SHIFT;
    int cbase = colbase[b];
    int cend  = colbase[b + 1];

    h[tid] = 0;
    __syncthreads();
    for (int e = cbase + tid; e < cend; e += 512)
        atomicAdd(&h[binned[e] & (BKT - 1)], 1);
    __syncthreads();

    int deg = h[tid];
    // two-level scan: wave-inclusive via shfl, then cross-wave via wsum
    int lane = tid & 63, wid = tid >> 6;
    int inc = deg;
#pragma unroll
    for (int off = 1; off < 64; off <<= 1) {
        int t = __shfl_up(inc, off);
        if (lane >= off) inc += t;
    }
    if (lane == 63) wsum[wid] = inc;
    __syncthreads();
    if (wid == 0) {
        int v = (lane < 8) ? wsum[lane] : 0;
#pragma unroll
        for (int off = 1; off < 8; off <<= 1) {
            int t = __shfl_up(v, off);
            if (lane >= off) v += t;
        }
        if (lane < 8) wsum[lane] = v;  // inclusive wave sums
    }
    __syncthreads();
    int incl = inc + (wid ? wsum[wid - 1] : 0);
    int excl = incl - deg;

    int node = base_node + tid;
    if (node < N) {
        dinv[node] = rsqrtf(1.0f + (float)deg);
        rp[node + 1] = cbase + incl;
    }
    h[tid] = excl;
    if (b == 0 && tid == 0) rp[0] = 0;
    __syncthreads();

    for (int e = cbase + tid; e < cend; e += 512) {
        unsigned r = binned[e];
        int slot = cbase + atomicAdd(&h[r & (BKT - 1)], 1);
        col[slot] = (int)(r >> BKT_SHIFT);
    }
}

// g = dinv .* x (row-wise pre-scale)
__global__ void k_prescale(const f4* __restrict__ x, const float* __restrict__ dinv,
                           f4* __restrict__ g, int N8) {
    int t = blockIdx.x * blockDim.x + threadIdx.x;
    if (t < N8) g[t] = dinv[t >> 3] * x[t];
}

// One hop on pre-scaled state: out[n] = sc * (sum_{s in N(n)} g[s] + g[n]),
// sc = dinv^2 (intermediate) or dinv (final). 8 lanes/row, unroll-4 MLP.
__global__ __launch_bounds__(256) void k_hop_gather(const int* __restrict__ rp,
                                                    const int* __restrict__ col,
                                                    const float* __restrict__ dinv,
                                                    const f4* __restrict__ gin,
                                                    f4* __restrict__ gout,
                                                    int N, int final_hop) {
    int t = blockIdx.x * blockDim.x + threadIdx.x;
    int n = t >> 3;
    if (n >= N) return;
    int q = t & 7;
    int e0 = rp[n], e1 = rp[n + 1];
    f4 a0 = gin[n * 8 + q];  // self-loop term
    f4 a1 = {0.f, 0.f, 0.f, 0.f};
    int e = e0;
    for (; e + 3 < e1; e += 4) {
        int s0 = col[e], s1 = col[e + 1], s2 = col[e + 2], s3 = col[e + 3];
        f4 h0 = gin[s0 * 8 + q];
        f4 h1 = gin[s1 * 8 + q];
        f4 h2 = gin[s2 * 8 + q];
        f4 h3 = gin[s3 * 8 + q];
        a0 += h0; a1 += h1; a0 += h2; a1 += h3;
    }
    for (; e < e1; ++e) a0 += gin[col[e] * 8 + q];
    float di = dinv[n];
    float sc = final_hop ? di : di * di;
    gout[n * 8 + q] = sc * (a0 + a1);
}

// out[n][o] = b[o] + sum_f h[n][f] * W[o][f]
__global__ __launch_bounds__(256) void k_linear(const float* __restrict__ h,
                                                const float* __restrict__ W,
                                                const float* __restrict__ b,
                                                float* __restrict__ out, int N) {
    __shared__ float Wl[F_OUT][F_IN + 1];
    __shared__ float hl[4][F_IN];
    int tid = threadIdx.x;
    for (int idx = tid; idx < F_OUT * F_IN; idx += 256) {
        Wl[idx >> 5][idx & 31] = W[idx];
    }
    int node0 = blockIdx.x * 4;
    if (tid < 4 * F_IN) {
        int n = tid >> 5, f = tid & 31;
        int node = node0 + n;
        hl[n][f] = (node < N) ? h[node * F_IN + f] : 0.0f;
    }
    __syncthreads();
    int n = tid >> 6;
    int o = tid & 63;
    int node = node0 + n;
    if (node < N) {
        float acc = b[o];
#pragma unroll
        for (int f = 0; f < F_IN; ++f) acc += hl[n][f] * Wl[o][f];
        out[node * F_OUT + o] = acc;
    }
}

extern "C" void kernel_launch(void* const* d_in, const int* in_sizes, int n_in,
                              void* d_out, int out_size, void* d_ws, size_t ws_size,
                              hipStream_t stream) {
    const float* x  = (const float*)d_in[0];
    const int*   ei = (const int*)d_in[1];   // [2,E] int32: src row then dst row
    const float* W  = (const float*)d_in[2];
    const float* b  = (const float*)d_in[3];
    float* out = (float*)d_out;

    const int N = in_sizes[0] / F_IN;
    const int E = in_sizes[1] / 2;
    const int NBKT = (N + BKT - 1) >> BKT_SHIFT;  // 196

    // d_ws: bcount(MAXB) | colbase(MAXB+1) | gcursor(MAXB) | rp(N+1) | dinv(N) | hA(N*32 f)
    int*   bcount  = (int*)d_ws;
    int*   colbase = bcount + MAXB;
    int*   gcursor = colbase + MAXB + 1;
    int*   rp      = gcursor + MAXB;
    float* dinv    = (float*)(rp + N + 1);
    float* hA      = (float*)(((uintptr_t)(dinv + N) + 255) & ~(uintptr_t)255);

    // d_out scratch: binned (E uint = 6.4MB, dies after fill3; reused as hB) |
    // col (E int = 6.4MB at +12.8MB). k_linear finally owns d_out.
    unsigned* binned = (unsigned*)d_out;
    float*    hB     = out;
    int*      col    = (int*)(out + (size_t)N * F_IN);

    const int B = 256;
    dim3 blk(B);
    dim3 gEPB((E + EPB - 1) / EPB);

    hipMemsetAsync(bcount, 0, MAXB * sizeof(int), stream);

    // bucket histogram + scan -> bases/cursors; bin edges (coalesced packed writes)
    k_bucket_hist<<<gEPB, blk, 0, stream>>>(ei + E, bcount, E);
    k_scan_buckets<<<dim3(1), dim3(MAXB), 0, stream>>>(bcount, colbase, gcursor);
    k_bin<<<gEPB, blk, 0, stream>>>(ei, gcursor, binned, E);

    // per-bucket counting sort: deg/dinv/rp/col, all XCD-local writes
    k_fill3<<<dim3(NBKT), dim3(512), 0, stream>>>(binned, colbase, dinv, rp, col, N);

    // pre-scale: g0 = dinv .* x -> hB
    const int N8 = N * 8;
    k_prescale<<<dim3((N8 + B - 1) / B), blk, 0, stream>>>((const f4*)x, dinv, (f4*)hB, N8);

    // hops: hB -> hA -> hB -> hA
    dim3 gHop(((size_t)N * 8 + B - 1) / B);
    k_hop_gather<<<gHop, blk, 0, stream>>>(rp, col, dinv, (const f4*)hB, (f4*)hA, N, 0);
    k_hop_gather<<<gHop, blk, 0, stream>>>(rp, col, dinv, (const f4*)hA, (f4*)hB, N, 0);
    k_hop_gather<<<gHop, blk, 0, stream>>>(rp, col, dinv, (const f4*)hB, (f4*)hA, N, 1);

    // linear: hA @ W^T + b -> out
    k_linear<<<dim3((N + 3) / 4), blk, 0, stream>>>(hA, W, b, out, N);
}

// Round 8
// 231.618 us; speedup vs baseline: 1.5999x; 1.0922x over previous
//
#include <hip/hip_runtime.h>

// SGConv: K=3 hops of \hat{A} x (symmetric gcn_norm w/ self-loops), then Linear.
// N=100000, E=1600000, F_in=32, F_out=64.
// Round 8: hops dominate (~66us each; 205MB random row-gathers at 3.3TB/s).
// Change: hop state in fp16 (_Float16), fp32 accumulate -> row 128B -> 64B,
// halving gather/write bytes. Diagnostic: neutral result => L3 line-fill bound.
// absmax budget: fp16 adds ~1-2e-3 vs 5.04e-3 threshold (was 9.8e-4).

#define F_IN 32
#define F_OUT 64
#define BKT_SHIFT 9                  // 512 nodes per dst-bucket
#define BKT (1 << BKT_SHIFT)
#define EPB 4096                     // edges per binning/histogram block
#define MAXB 256                     // >= number of buckets (196 for N=100000)

typedef float f4 __attribute__((ext_vector_type(4)));
typedef _Float16 h4 __attribute__((ext_vector_type(4)));  // 8B: 4 halves

// Per-block LDS histogram of dst-buckets -> MAXB global atomics per block.
__global__ __launch_bounds__(256) void k_bucket_hist(const int* __restrict__ dst,
                                                     int* __restrict__ bcount, int E) {
    __shared__ int h[MAXB];
    int tid = threadIdx.x;
    h[tid] = 0;
    __syncthreads();
    int base = blockIdx.x * EPB;
    for (int k = 0; k < EPB / 256; ++k) {
        int i = base + k * 256 + tid;
        if (i < E) atomicAdd(&h[dst[i] >> BKT_SHIFT], 1);
    }
    __syncthreads();
    if (h[tid]) atomicAdd(&bcount[tid], h[tid]);
}

// One block (MAXB threads): exclusive scan of bucket counts.
__global__ __launch_bounds__(MAXB) void k_scan_buckets(const int* __restrict__ bcount,
                                                       int* __restrict__ colbase,
                                                       int* __restrict__ gcursor) {
    __shared__ int sc[MAXB];
    int tid = threadIdx.x;
    int c = bcount[tid];
    sc[tid] = c;
    __syncthreads();
    for (int off = 1; off < MAXB; off <<= 1) {
        int t = (tid >= off) ? sc[tid - off] : 0;
        __syncthreads();
        sc[tid] += t;
        __syncthreads();
    }
    int excl = sc[tid] - c;
    colbase[tid] = excl;
    gcursor[tid] = excl;
    if (tid == MAXB - 1) colbase[MAXB] = sc[tid];
}

// Bin edges into dst-buckets; records packed to 4B: (src << 9) | (dst & 511).
__global__ __launch_bounds__(256) void k_bin(const int* __restrict__ ei,
                                             int* __restrict__ gcursor,
                                             unsigned* __restrict__ binned, int E) {
    __shared__ unsigned stage[EPB];          // 16 KB
    __shared__ unsigned char bid[EPB];       // 4 KB
    __shared__ int hist[MAXB], lscan[MAXB], lbase[MAXB], fcur[MAXB], sc[MAXB];
    int tid = threadIdx.x;
    int base = blockIdx.x * EPB;
    int cnt = E - base; if (cnt > EPB) cnt = EPB;

    hist[tid] = 0;
    __syncthreads();
    for (int k = 0; k < EPB / 256; ++k) {
        int i = base + k * 256 + tid;
        if (i < E) atomicAdd(&hist[ei[E + i] >> BKT_SHIFT], 1);
    }
    __syncthreads();
    sc[tid] = hist[tid];
    __syncthreads();
    for (int off = 1; off < MAXB; off <<= 1) {
        int t = (tid >= off) ? sc[tid - off] : 0;
        __syncthreads();
        sc[tid] += t;
        __syncthreads();
    }
    {
        int excl = sc[tid] - hist[tid];
        lscan[tid] = excl;
        fcur[tid] = excl;
        lbase[tid] = hist[tid] ? atomicAdd(&gcursor[tid], hist[tid]) : 0;
    }
    __syncthreads();
    for (int k = 0; k < EPB / 256; ++k) {
        int i = base + k * 256 + tid;
        if (i < E) {
            unsigned s = (unsigned)ei[i];
            unsigned d = (unsigned)ei[E + i];
            int b = d >> BKT_SHIFT;
            int loc = atomicAdd(&fcur[b], 1);
            stage[loc] = (s << BKT_SHIFT) | (d & (BKT - 1));
            bid[loc] = (unsigned char)b;
        }
    }
    __syncthreads();
    for (int k = 0; k < EPB / 256; ++k) {
        int idx = k * 256 + tid;
        if (idx < cnt) {
            int b = bid[idx];
            binned[lbase[b] + (idx - lscan[b])] = stage[idx];
        }
    }
}

// One workgroup (512 thr) per 512-node bucket: LDS hist -> shfl scan ->
// dinv/rp (coalesced) -> col scatter via LDS cursors. No global atomics.
__global__ __launch_bounds__(512) void k_fill3(const unsigned* __restrict__ binned,
                                               const int* __restrict__ colbase,
                                               float* __restrict__ dinv,
                                               int* __restrict__ rp,
                                               int* __restrict__ col, int N) {
    __shared__ int h[BKT];
    __shared__ int wsum[8];
    int tid = threadIdx.x;
    int b = blockIdx.x;
    int base_node = b << BKT_SHIFT;
    int cbase = colbase[b];
    int cend  = colbase[b + 1];

    h[tid] = 0;
    __syncthreads();
    for (int e = cbase + tid; e < cend; e += 512)
        atomicAdd(&h[binned[e] & (BKT - 1)], 1);
    __syncthreads();

    int deg = h[tid];
    int lane = tid & 63, wid = tid >> 6;
    int inc = deg;
#pragma unroll
    for (int off = 1; off < 64; off <<= 1) {
        int t = __shfl_up(inc, off);
        if (lane >= off) inc += t;
    }
    if (lane == 63) wsum[wid] = inc;
    __syncthreads();
    if (wid == 0) {
        int v = (lane < 8) ? wsum[lane] : 0;
#pragma unroll
        for (int off = 1; off < 8; off <<= 1) {
            int t = __shfl_up(v, off);
            if (lane >= off) v += t;
        }
        if (lane < 8) wsum[lane] = v;
    }
    __syncthreads();
    int incl = inc + (wid ? wsum[wid - 1] : 0);
    int excl = incl - deg;

    int node = base_node + tid;
    if (node < N) {
        dinv[node] = rsqrtf(1.0f + (float)deg);
        rp[node + 1] = cbase + incl;
    }
    h[tid] = excl;
    if (b == 0 && tid == 0) rp[0] = 0;
    __syncthreads();

    for (int e = cbase + tid; e < cend; e += 512) {
        unsigned r = binned[e];
        int slot = cbase + atomicAdd(&h[r & (BKT - 1)], 1);
        col[slot] = (int)(r >> BKT_SHIFT);
    }
}

// g0 = fp16(dinv .* x): read f4, write h4.
__global__ void k_prescale(const f4* __restrict__ x, const float* __restrict__ dinv,
                           h4* __restrict__ g, int N8) {
    int t = blockIdx.x * blockDim.x + threadIdx.x;
    if (t < N8) {
        f4 v = dinv[t >> 3] * x[t];
        g[t] = __builtin_convertvector(v, h4);
    }
}

// One hop on pre-scaled fp16 state, fp32 accumulate:
// out[n] = sc * (sum_{s in N(n)} g[s] + g[n]); sc = dinv^2 or dinv (final).
// 8 lanes/row (8B each -> 64B row), unroll-4 MLP.
__global__ __launch_bounds__(256) void k_hop_gather(const int* __restrict__ rp,
                                                    const int* __restrict__ col,
                                                    const float* __restrict__ dinv,
                                                    const h4* __restrict__ gin,
                                                    h4* __restrict__ gout,
                                                    int N, int final_hop) {
    int t = blockIdx.x * blockDim.x + threadIdx.x;
    int n = t >> 3;
    if (n >= N) return;
    int q = t & 7;
    int e0 = rp[n], e1 = rp[n + 1];
    f4 a0 = __builtin_convertvector(gin[n * 8 + q], f4);  // self-loop term
    f4 a1 = {0.f, 0.f, 0.f, 0.f};
    int e = e0;
    for (; e + 3 < e1; e += 4) {
        int s0 = col[e], s1 = col[e + 1], s2 = col[e + 2], s3 = col[e + 3];
        h4 h0 = gin[s0 * 8 + q];
        h4 h1 = gin[s1 * 8 + q];
        h4 h2 = gin[s2 * 8 + q];
        h4 h3 = gin[s3 * 8 + q];
        a0 += __builtin_convertvector(h0, f4);
        a1 += __builtin_convertvector(h1, f4);
        a0 += __builtin_convertvector(h2, f4);
        a1 += __builtin_convertvector(h3, f4);
    }
    for (; e < e1; ++e) a0 += __builtin_convertvector(gin[col[e] * 8 + q], f4);
    float di = dinv[n];
    float sc = final_hop ? di : di * di;
    f4 r = sc * (a0 + a1);
    gout[n * 8 + q] = __builtin_convertvector(r, h4);
}

// out[n][o] = b[o] + sum_f h[n][f] * W[o][f]; h is fp16.
__global__ __launch_bounds__(256) void k_linear(const _Float16* __restrict__ h,
                                                const float* __restrict__ W,
                                                const float* __restrict__ b,
                                                float* __restrict__ out, int N) {
    __shared__ float Wl[F_OUT][F_IN + 1];
    __shared__ float hl[4][F_IN];
    int tid = threadIdx.x;
    for (int idx = tid; idx < F_OUT * F_IN; idx += 256) {
        Wl[idx >> 5][idx & 31] = W[idx];
    }
    int node0 = blockIdx.x * 4;
    if (tid < 4 * F_IN) {
        int n = tid >> 5, f = tid & 31;
        int node = node0 + n;
        hl[n][f] = (node < N) ? (float)h[node * F_IN + f] : 0.0f;
    }
    __syncthreads();
    int n = tid >> 6;
    int o = tid & 63;
    int node = node0 + n;
    if (node < N) {
        float acc = b[o];
#pragma unroll
        for (int f = 0; f < F_IN; ++f) acc += hl[n][f] * Wl[o][f];
        out[node * F_OUT + o] = acc;
    }
}

extern "C" void kernel_launch(void* const* d_in, const int* in_sizes, int n_in,
                              void* d_out, int out_size, void* d_ws, size_t ws_size,
                              hipStream_t stream) {
    const float* x  = (const float*)d_in[0];
    const int*   ei = (const int*)d_in[1];   // [2,E] int32: src row then dst row
    const float* W  = (const float*)d_in[2];
    const float* b  = (const float*)d_in[3];
    float* out = (float*)d_out;

    const int N = in_sizes[0] / F_IN;
    const int E = in_sizes[1] / 2;
    const int NBKT = (N + BKT - 1) >> BKT_SHIFT;  // 196

    // d_ws: bcount(MAXB) | colbase(MAXB+1) | gcursor(MAXB) | rp(N+1) | dinv(N) |
    //       hA (N*32 fp16 = 6.4MB)
    int*   bcount  = (int*)d_ws;
    int*   colbase = bcount + MAXB;
    int*   gcursor = colbase + MAXB + 1;
    int*   rp      = gcursor + MAXB;
    float* dinv    = (float*)(rp + N + 1);
    _Float16* hA   = (_Float16*)(((uintptr_t)(dinv + N) + 255) & ~(uintptr_t)255);

    // d_out scratch: binned (E uint = 6.4MB; dies after fill3, reused as hB fp16) |
    // col (E int = 6.4MB at +12.8MB). k_linear finally owns d_out.
    unsigned* binned = (unsigned*)d_out;
    _Float16* hB     = (_Float16*)d_out;
    int*      col    = (int*)(out + (size_t)N * F_IN);

    const int B = 256;
    dim3 blk(B);
    dim3 gEPB((E + EPB - 1) / EPB);

    hipMemsetAsync(bcount, 0, MAXB * sizeof(int), stream);

    // bucket histogram + scan -> bases/cursors; bin edges (coalesced packed writes)
    k_bucket_hist<<<gEPB, blk, 0, stream>>>(ei + E, bcount, E);
    k_scan_buckets<<<dim3(1), dim3(MAXB), 0, stream>>>(bcount, colbase, gcursor);
    k_bin<<<gEPB, blk, 0, stream>>>(ei, gcursor, binned, E);

    // per-bucket counting sort: deg/dinv/rp/col, all XCD-local writes
    k_fill3<<<dim3(NBKT), dim3(512), 0, stream>>>(binned, colbase, dinv, rp, col, N);

    // pre-scale: g0 = fp16(dinv .* x) -> hA (ws; binned in d_out still live until fill3 done,
    // and hB aliases binned, so first hop target order is hA -> hB)
    const int N8 = N * 8;
    k_prescale<<<dim3((N8 + B - 1) / B), blk, 0, stream>>>((const f4*)x, dinv, (h4*)hA, N8);

    // hops: hA -> hB -> hA -> hB ... need final in ws for k_linear; use hA->hB->hA? 3 hops:
    // hA -> hB, hB -> hA, hA -> hB would end in d_out (clobbered by linear). End in hA:
    // prescale->hA, hop1 hA->hB, hop2 hB->hA, hop3 hA->hB? ends hB. Instead prescale->hB
    // is unsafe (binned live). So: hop1 hA->hB, hop2 hB->hA, hop3 hA->hB, and k_linear
    // reads hB BEFORE writing out? k_linear writes out[node] after reading h[node] of the
    // same block only -- unsafe across blocks. Final must be in ws: do 3 hops as
    // hA->hB, hB->hA, hA->hB is wrong; use hA->hB, hB->hA, then final hA->hA? No.
    // Simplest safe chain: hop1 hA->hB, hop2 hB->hA, hop3 hA->hB with hB2 = hA+N*32
    // (second ws fp16 buffer, 6.4MB). Final lands in ws.
    {
        _Float16* hB2 = hA + (size_t)N * F_IN;  // second fp16 buffer in ws
        dim3 gHop(((size_t)N * 8 + B - 1) / B);
        k_hop_gather<<<gHop, blk, 0, stream>>>(rp, col, dinv, (const h4*)hA, (h4*)hB, N, 0);
        k_hop_gather<<<gHop, blk, 0, stream>>>(rp, col, dinv, (const h4*)hB, (h4*)hB2, N, 0);
        k_hop_gather<<<gHop, blk, 0, stream>>>(rp, col, dinv, (const h4*)hB2, (h4*)hA, N, 1);
        k_linear<<<dim3((N + 3) / 4), blk, 0, stream>>>(hA, W, b, out, N);
    }
}